// Round 2
// baseline (4134.525 us; speedup 1.0000x reference)
//
#include <hip/hip_runtime.h>
#include <hip/hip_bf16.h>
#include <math.h>

// ---------------- problem constants ----------------
#define NTOK 401408              // 8*1024*49 tokens
#define NWIN 8192                // 8*1024 windows
#define NCHUNK 4
#define TOK_PER_CHUNK (NTOK / NCHUNK)   // 100352
#define WIN_PER_CHUNK (NWIN / NCHUNK)   // 2048

typedef __attribute__((ext_vector_type(8))) short bf16x8_t;
typedef __attribute__((ext_vector_type(4))) float f32x4_t;

__device__ __forceinline__ float bf2f(unsigned int u) {
    return __uint_as_float(u << 16);
}
__device__ __forceinline__ unsigned short f2bf(float f) {
    unsigned int x = __float_as_uint(f);
    x += 0x7fffu + ((x >> 16) & 1u);   // RNE
    return (unsigned short)(x >> 16);
}
__device__ __forceinline__ void unpack8(const unsigned short* p, float* f) {
    uint4 u = *(const uint4*)p;
    f[0] = bf2f(u.x & 0xffffu); f[1] = bf2f(u.x >> 16);
    f[2] = bf2f(u.y & 0xffffu); f[3] = bf2f(u.y >> 16);
    f[4] = bf2f(u.z & 0xffffu); f[5] = bf2f(u.z >> 16);
    f[6] = bf2f(u.w & 0xffffu); f[7] = bf2f(u.w >> 16);
}

// ---------------- weight transpose + bf16 cast:  WT[n][k] = W[k][n] ----------------
__global__ void wt_kernel(const float* __restrict__ W, unsigned short* __restrict__ WT,
                          int K, int N) {
    int i = blockIdx.x * 256 + threadIdx.x;
    if (i >= N * K) return;
    int n = i / K, k = i - n * K;
    WT[i] = f2bf(W[(size_t)k * N + n]);
}

// ---------------- LayerNorm over 192 channels, 1 wave / token ----------------
template<int IN_BF16>
__global__ __launch_bounds__(256) void ln_kernel(const void* __restrict__ in,
                                                 unsigned short* __restrict__ out,
                                                 const float* __restrict__ g,
                                                 const float* __restrict__ b) {
    int tok  = blockIdx.x * 4 + (threadIdx.x >> 6);
    int lane = threadIdx.x & 63;
    float x0, x1, x2;
    if (IN_BF16) {
        const unsigned short* p = (const unsigned short*)in + (size_t)tok * 192;
        x0 = bf2f(p[lane]); x1 = bf2f(p[lane + 64]); x2 = bf2f(p[lane + 128]);
    } else {
        const float* p = (const float*)in + (size_t)tok * 192;
        x0 = p[lane]; x1 = p[lane + 64]; x2 = p[lane + 128];
    }
    float s  = x0 + x1 + x2;
    float sq = x0 * x0 + x1 * x1 + x2 * x2;
    for (int o = 32; o; o >>= 1) { s += __shfl_xor(s, o); sq += __shfl_xor(sq, o); }
    float m   = s * (1.f / 192.f);
    float var = sq * (1.f / 192.f) - m * m;
    float r   = rsqrtf(var + 1e-5f);
    unsigned short* q = out + (size_t)tok * 192;
    q[lane]       = f2bf((x0 - m) * r * g[lane]       + b[lane]);
    q[lane + 64]  = f2bf((x1 - m) * r * g[lane + 64]  + b[lane + 64]);
    q[lane + 128] = f2bf((x2 - m) * r * g[lane + 128] + b[lane + 128]);
}

// ---------------- MFMA GEMM: C[M,N] = A[M,K] @ W[K,N] + bias, fused epilogues ----------------
// A bf16 row-major (chunk-local), WT bf16 [N][K]. 128x64 tile, BK=32, 4 waves.
#define EP_QKV     0   // + bias -> bf16 out (ld = NDIM)
#define EP_PROJ    1   // + bias + f32 residual -> bf16 out (ld 192)
#define EP_MLP1    2   // + bias, exact GELU -> bf16 out (ld = NDIM)
#define EP_MLP2_B1 3   // + bias + bf16 residual -> f32 out with intra-window roll(+4,+4)
#define EP_MLP2_B2 4   // + bias + bf16 residual -> f32 out with final roll (w+3, c+3)

template<int NDIM, int KDIM, int EP>
__global__ __launch_bounds__(256) void gemm_kernel(const unsigned short* __restrict__ A,
                                                   const unsigned short* __restrict__ WT,
                                                   const float* __restrict__ bias,
                                                   const void* __restrict__ res,
                                                   void* __restrict__ out,
                                                   int row0) {
    __shared__ unsigned short As[128][40];   // +8 pad: conflict-free ds_read_b128
    __shared__ unsigned short Bs[64][40];
    int tid  = threadIdx.x;
    int wave = tid >> 6, lane = tid & 63;
    int wm = wave >> 1, wn = wave & 1;
    int rowBase = blockIdx.x * 128;          // chunk-local
    int colBase = blockIdx.y * 64;
    int kq = lane >> 4, lr = lane & 15;

    f32x4_t acc[4][2] = {};
    for (int k0 = 0; k0 < KDIM; k0 += 32) {
        __syncthreads();
        #pragma unroll
        for (int s = 0; s < 2; ++s) {                       // A: 512 x 16B
            int id = tid + s * 256;
            int r = id >> 2, pp = id & 3;
            *(uint4*)&As[r][pp * 8] =
                *(const uint4*)(A + (size_t)(rowBase + r) * KDIM + k0 + pp * 8);
        }
        {                                                   // B: 256 x 16B
            int r = tid >> 2, pp = tid & 3;
            *(uint4*)&Bs[r][pp * 8] =
                *(const uint4*)(WT + (size_t)(colBase + r) * KDIM + k0 + pp * 8);
        }
        __syncthreads();
        bf16x8_t afr[4], bfr[2];
        #pragma unroll
        for (int mi = 0; mi < 4; ++mi)
            afr[mi] = *(const bf16x8_t*)&As[wm * 64 + mi * 16 + lr][kq * 8];
        #pragma unroll
        for (int ni = 0; ni < 2; ++ni)
            bfr[ni] = *(const bf16x8_t*)&Bs[wn * 32 + ni * 16 + lr][kq * 8];
        #pragma unroll
        for (int mi = 0; mi < 4; ++mi)
            #pragma unroll
            for (int ni = 0; ni < 2; ++ni)
                acc[mi][ni] = __builtin_amdgcn_mfma_f32_16x16x32_bf16(
                    afr[mi], bfr[ni], acc[mi][ni], 0, 0, 0);
    }

    #pragma unroll
    for (int mi = 0; mi < 4; ++mi) {
        #pragma unroll
        for (int ni = 0; ni < 2; ++ni) {
            int col = colBase + wn * 32 + ni * 16 + lr;
            float bcol = bias[col];
            #pragma unroll
            for (int r = 0; r < 4; ++r) {
                int rloc = rowBase + wm * 64 + mi * 16 + kq * 4 + r;
                float v = acc[mi][ni][r] + bcol;
                if (EP == EP_QKV) {
                    ((unsigned short*)out)[(size_t)rloc * NDIM + col] = f2bf(v);
                } else if (EP == EP_PROJ) {
                    v += ((const float*)res)[(size_t)rloc * 192 + col];
                    ((unsigned short*)out)[(size_t)rloc * 192 + col] = f2bf(v);
                } else if (EP == EP_MLP1) {
                    float gl = 0.5f * v * (1.f + erff(v * 0.70710678118654752f));
                    ((unsigned short*)out)[(size_t)rloc * NDIM + col] = f2bf(gl);
                } else {
                    v += bf2f((unsigned int)((const unsigned short*)res)[(size_t)rloc * 192 + col]);
                    int grow = row0 + rloc;
                    int win = grow / 49;
                    int pp  = grow - win * 49;
                    int h = pp / 7, w = pp - h * 7;
                    if (EP == EP_MLP2_B1) {
                        int h2 = h + 4; if (h2 >= 7) h2 -= 7;
                        int w2 = w + 4; if (w2 >= 7) w2 -= 7;
                        ((float*)out)[((size_t)win * 49 + h2 * 7 + w2) * 192 + col] = v;
                    } else {
                        int w2 = w + 3; if (w2 >= 7) w2 -= 7;
                        int c2 = col + 3; if (c2 >= 192) c2 -= 192;
                        ((float*)out)[((size_t)win * 49 + h * 7 + w2) * 192 + c2] = v;
                    }
                }
            }
        }
    }
}

// ---------------- window attention: 1 wave per (window, head), VALU ----------------
template<int MASKED>
__global__ __launch_bounds__(64) void attn_kernel(const unsigned short* __restrict__ qkv,
                                                  const float* __restrict__ bias_table,
                                                  unsigned short* __restrict__ outp,
                                                  int win0) {
    __shared__ unsigned short q_s[49][32];
    __shared__ unsigned short k_s[49][32];
    __shared__ unsigned short v_s[49][32];
    __shared__ float sc[49][52];
    __shared__ float bl[169];
    int wloc = blockIdx.x, head = blockIdx.y, lane = threadIdx.x;

    const unsigned short* wq = qkv + (size_t)wloc * 49 * 576 + head * 32;
    for (int idx = lane; idx < 196; idx += 64) {
        int t = idx >> 2, pp = idx & 3;
        const unsigned short* s = wq + (size_t)t * 576 + pp * 8;
        *(uint4*)&q_s[t][pp * 8] = *(const uint4*)(s);
        *(uint4*)&k_s[t][pp * 8] = *(const uint4*)(s + 192);
        *(uint4*)&v_s[t][pp * 8] = *(const uint4*)(s + 384);
    }
    for (int i = lane; i < 169; i += 64) bl[i] = bias_table[i * 6 + head];
    __syncthreads();

    int r = lane;
    if (r < 49) {
        float q[32];
        #pragma unroll
        for (int pp = 0; pp < 4; ++pp) unpack8(&q_s[r][pp * 8], &q[pp * 8]);
        int rh = r / 7, rw = r - rh * 7;
        int rid_r = 2 * (rh >= 4) + (rw >= 4);
        for (int c = 0; c < 49; ++c) {
            float kk[32];
            #pragma unroll
            for (int pp = 0; pp < 4; ++pp) unpack8(&k_s[c][pp * 8], &kk[pp * 8]);
            float a = 0.f;
            #pragma unroll
            for (int d = 0; d < 32; ++d) a += q[d] * kk[d];
            int ch = c / 7, cw = c - ch * 7;
            a = a * 0.17677669529663687f + bl[(rh - ch + 6) * 13 + (rw - cw + 6)];
            if (MASKED) {
                int rid_c = 2 * (ch >= 4) + (cw >= 4);
                if (rid_c != rid_r) a -= 100.f;
            }
            sc[r][c] = a;
        }
        float m = sc[r][0];
        for (int c = 1; c < 49; ++c) m = fmaxf(m, sc[r][c]);
        float ssum = 0.f;
        for (int c = 0; c < 49; ++c) { float e = __expf(sc[r][c] - m); sc[r][c] = e; ssum += e; }
        float inv = 1.f / ssum;

        float o[32] = {};
        for (int c = 0; c < 49; ++c) {
            float a = sc[r][c] * inv;
            float vv[32];
            #pragma unroll
            for (int pp = 0; pp < 4; ++pp) unpack8(&v_s[c][pp * 8], &vv[pp * 8]);
            #pragma unroll
            for (int d = 0; d < 32; ++d) o[d] += a * vv[d];
        }
        size_t tok = (size_t)(win0 + wloc) * 49 + r;
        unsigned short* op = outp + tok * 192 + head * 32;
        unsigned int pk[16];
        #pragma unroll
        for (int d = 0; d < 16; ++d)
            pk[d] = (unsigned int)f2bf(o[2 * d]) | ((unsigned int)f2bf(o[2 * d + 1]) << 16);
        #pragma unroll
        for (int pp = 0; pp < 4; ++pp) {
            uint4 u; u.x = pk[pp*4]; u.y = pk[pp*4+1]; u.z = pk[pp*4+2]; u.w = pk[pp*4+3];
            *(uint4*)(op + pp * 8) = u;
        }
    }
}

// ---------------- host launch ----------------
extern "C" void kernel_launch(void* const* d_in, const int* in_sizes, int n_in,
                              void* d_out, int out_size, void* d_ws, size_t ws_size,
                              hipStream_t stream) {
    (void)in_sizes; (void)n_in; (void)out_size; (void)ws_size;
    const float* X     = (const float*)d_in[0];
    const float* ln1_g = (const float*)d_in[1];
    const float* ln1_b = (const float*)d_in[2];
    const float* ln2_g = (const float*)d_in[3];
    const float* ln2_b = (const float*)d_in[4];
    const float* qkv_w[2]  = { (const float*)d_in[5],  (const float*)d_in[10] };
    const float* qkv_b[2]  = { (const float*)d_in[6],  (const float*)d_in[11] };
    const float* proj_w[2] = { (const float*)d_in[7],  (const float*)d_in[12] };
    const float* proj_b[2] = { (const float*)d_in[8],  (const float*)d_in[13] };
    const float* btab[2]   = { (const float*)d_in[9],  (const float*)d_in[14] };
    const float* w1 = (const float*)d_in[15];
    const float* b1 = (const float*)d_in[16];
    const float* w2 = (const float*)d_in[17];
    const float* b2 = (const float*)d_in[18];

    char* p = (char*)d_ws;
    auto take = [&](size_t elems) -> unsigned short* {
        unsigned short* r = (unsigned short*)p;
        p += (elems * 2 + 255) & ~(size_t)255;
        return r;
    };
    unsigned short* WTq[2]; unsigned short* WTp[2];
    WTq[0] = take(576 * 192); WTp[0] = take(192 * 192);
    WTq[1] = take(576 * 192); WTp[1] = take(192 * 192);
    unsigned short* WT1 = take(768 * 192);
    unsigned short* WT2 = take(192 * 768);
    unsigned short* B0 = take((size_t)NTOK * 192);            // ln1 out -> attn out -> ln2 out
    unsigned short* B1 = take((size_t)TOK_PER_CHUNK * 768);   // qkv chunk / proj out (full) / mlp hidden chunk
    // NOTE: TOK_PER_CHUNK*768 == NTOK*192, so B1 also holds the full-width proj output.

    auto tr = [&](const float* src, unsigned short* dst, int K, int N) {
        int n = K * N;
        wt_kernel<<<dim3((n + 255) / 256), dim3(256), 0, stream>>>(src, dst, K, N);
    };
    tr(qkv_w[0],  WTq[0], 192, 576);
    tr(proj_w[0], WTp[0], 192, 192);
    tr(qkv_w[1],  WTq[1], 192, 576);
    tr(proj_w[1], WTp[1], 192, 192);
    tr(w1, WT1, 192, 768);
    tr(w2, WT2, 768, 192);

    float* Xcur = (float*)d_out;   // f32 trunk between blocks lives in d_out

    for (int blk = 0; blk < 2; ++blk) {
        const float* Xin = (blk == 0) ? X : (const float*)Xcur;

        ln_kernel<0><<<dim3(NTOK / 4), dim3(256), 0, stream>>>((const void*)Xin, B0, ln1_g, ln1_b);

        for (int c = 0; c < NCHUNK; ++c) {
            size_t row0 = (size_t)c * TOK_PER_CHUNK;
            gemm_kernel<576, 192, EP_QKV><<<dim3(TOK_PER_CHUNK / 128, 9), dim3(256), 0, stream>>>(
                B0 + row0 * 192, WTq[blk], qkv_b[blk], nullptr, (void*)B1, (int)row0);
            if (blk == 0)
                attn_kernel<0><<<dim3(WIN_PER_CHUNK, 6), dim3(64), 0, stream>>>(
                    B1, btab[blk], B0, c * WIN_PER_CHUNK);
            else
                attn_kernel<1><<<dim3(WIN_PER_CHUNK, 6), dim3(64), 0, stream>>>(
                    B1, btab[blk], B0, c * WIN_PER_CHUNK);
        }

        // PROJ: reads A=B0 (attn out), res=Xin, writes B1 (NOT in-place: sibling
        // y-blocks read the full K range of A, so in-place B0->B0 races).
        gemm_kernel<192, 192, EP_PROJ><<<dim3(NTOK / 128, 3), dim3(256), 0, stream>>>(
            B0, WTp[blk], proj_b[blk], (const void*)Xin, (void*)B1, 0);

        // LN2: B1 (bf16 X2) -> B0
        ln_kernel<1><<<dim3(NTOK / 4), dim3(256), 0, stream>>>((const void*)B1, B0, ln2_g, ln2_b);

        for (int c = 0; c < NCHUNK; ++c) {
            size_t row0 = (size_t)c * TOK_PER_CHUNK;
            gemm_kernel<768, 192, EP_MLP1><<<dim3(TOK_PER_CHUNK / 128, 12), dim3(256), 0, stream>>>(
                B0 + row0 * 192, WT1, b1, nullptr, (void*)B1, (int)row0);
            if (blk == 0)
                gemm_kernel<192, 768, EP_MLP2_B1><<<dim3(TOK_PER_CHUNK / 128, 3), dim3(256), 0, stream>>>(
                    B1, WT2, b2, (const void*)(B0 + row0 * 192), (void*)Xcur, (int)row0);
            else
                gemm_kernel<192, 768, EP_MLP2_B2><<<dim3(TOK_PER_CHUNK / 128, 3), dim3(256), 0, stream>>>(
                    B1, WT2, b2, (const void*)(B0 + row0 * 192), (void*)d_out, (int)row0);
        }
    }
}